// Round 2
// baseline (533.875 us; speedup 1.0000x reference)
//
#include <hip/hip_runtime.h>
#include <cstdint>
#include <cstddef>

#define B_   2
#define L_   4096
#define DM_  1024
#define DI_  2048
#define DT_  64
#define M_   (B_*L_)      // 8192 rows
#define G_   64           // scan chunks per row
#define CH_  (L_/G_)      // 64 elements per chunk

typedef __bf16 bf16;
typedef __bf16 bf16x8 __attribute__((ext_vector_type(8)));
typedef __bf16 bf16x4 __attribute__((ext_vector_type(4)));
typedef float  f32x4  __attribute__((ext_vector_type(4)));

__device__ __forceinline__ float silu_f(float x){ return x / (1.f + __expf(-x)); }

// ---------------- fp32 -> bf16 conversion (4-wide) ----------------
__global__ __launch_bounds__(256)
void cvt4_kernel(const float4* __restrict__ s, bf16x4* __restrict__ d, int n4){
  int i = blockIdx.x*256 + threadIdx.x;
  if (i < n4){
    float4 v = s[i];
    bf16x4 o = {(bf16)v.x, (bf16)v.y, (bf16)v.z, (bf16)v.w};
    d[i] = o;
  }
}

// ---------------- GEMM: C[M,N] = A[M,K] * W[N,K]^T, bf16 MFMA ----------------
// 128x128 macro-tile, BK=32, 256 threads = 4 waves in 2x2, each wave 64x64
// via 4x4 grid of v_mfma_f32_16x16x32_bf16. LDS rows padded to 40 elems
// (80B = 5*16B: keeps 16B alignment, breaks power-of-2-stride bank conflicts).
#define BK_ 32
#define LDP 40

template<int EPI>
__global__ __launch_bounds__(256)
void gemm_bt(const bf16* __restrict__ A, const bf16* __restrict__ W,
             int M, int N, int K,
             float* __restrict__ o0, bf16* __restrict__ ob,
             const float* __restrict__ bias, const float* __restrict__ alog)
{
  __shared__ bf16 As[128*LDP];
  __shared__ bf16 Bs[128*LDP];
  const int t    = threadIdx.x;
  const int lane = t & 63;
  const int wave = t >> 6;
  const int wm   = wave >> 1, wn = wave & 1;
  const int l16  = lane & 15, quad = lane >> 4;
  const int m0   = blockIdx.y * 128, n0 = blockIdx.x * 128;

  f32x4 acc[4][4] = {};

  const int kframes = K / BK_;
  for (int kt = 0; kt < kframes; ++kt){
    const int k0 = kt * BK_;
    #pragma unroll
    for (int i = 0; i < 2; ++i){
      const int f   = i*256 + t;          // 16B chunk id, 0..511
      const int row = f >> 2;             // 0..127
      const int col = (f & 3) * 8;        // 0,8,16,24
      int rA = m0 + row; if (rA >= M) rA = M - 1;
      int rB = n0 + row; if (rB >= N) rB = N - 1;   // clamp for N<128 tiles
      bf16x8 va = *(const bf16x8*)(A + (size_t)rA*K + k0 + col);
      bf16x8 vb = *(const bf16x8*)(W + (size_t)rB*K + k0 + col);
      *(bf16x8*)&As[row*LDP + col] = va;
      *(bf16x8*)&Bs[row*LDP + col] = vb;
    }
    __syncthreads();
    bf16x8 af[4], bf_[4];
    #pragma unroll
    for (int i = 0; i < 4; ++i){
      af[i]  = *(const bf16x8*)&As[(wm*64 + i*16 + l16)*LDP + quad*8];
      bf_[i] = *(const bf16x8*)&Bs[(wn*64 + i*16 + l16)*LDP + quad*8];
    }
    #pragma unroll
    for (int mi = 0; mi < 4; ++mi)
      #pragma unroll
      for (int ni = 0; ni < 4; ++ni)
        acc[mi][ni] = __builtin_amdgcn_mfma_f32_16x16x32_bf16(af[mi], bf_[ni], acc[mi][ni], 0, 0, 0);
    __syncthreads();
  }

  // C/D layout (m89/m91 verified): col = lane&15, row = (lane>>4)*4 + reg
  #pragma unroll
  for (int mi = 0; mi < 4; ++mi){
    #pragma unroll
    for (int ni = 0; ni < 4; ++ni){
      const int n = n0 + wn*64 + ni*16 + l16;
      if (n < N){
        #pragma unroll
        for (int r = 0; r < 4; ++r){
          const int m = m0 + wm*64 + mi*16 + quad*4 + r;
          float v = acc[mi][ni][r];
          if (EPI == 0){
            // in_proj split: n<DI -> xi_raw fp32 (o0), n>=DI -> g = silu(z) bf16 (ob)
            if (n < DI_) o0[(size_t)m*DI_ + n] = v;
            else         ob[(size_t)m*DI_ + (n - DI_)] = (bf16)silu_f(v);
          } else if (EPI == 1){
            ob[(size_t)m*N + n] = (bf16)v;            // dt_low (bf16)
          } else if (EPI == 2){
            // delta = clip(softplus(v + b), 1e-6, 10); e = clip(exp(delta*A), 1e-6, 1)
            float vv = v + bias[n];
            float delta = (vv > 20.f) ? vv : log1pf(__expf(vv));
            delta = fminf(fmaxf(delta, 1e-6f), 10.f);
            float Ad = -__expf(alog[n]);
            Ad = fminf(fmaxf(Ad, -10.f), -1e-6f);
            float ee = __expf(delta * Ad);
            o0[(size_t)m*N + n] = fminf(fmaxf(ee, 1e-6f), 1.f);   // e fp32
          } else {
            o0[(size_t)m*N + n] = v;                  // final output fp32
          }
        }
      }
    }
  }
}

// ---------------- depthwise causal conv (K=4) + bias + SiLU ----------------
__global__ __launch_bounds__(256)
void conv_silu_kernel(const float* __restrict__ xi, const float* __restrict__ cw,
                      const float* __restrict__ cb, bf16* __restrict__ ubf)
{
  const int idx = blockIdx.x*256 + threadIdx.x;    // (b,l,d) flat, coalesced in d
  const int d = idx & (DI_-1);
  const int l = (idx >> 11) & (L_-1);              // DI_=2^11, L_=2^12
  float s = cb[d];
  #pragma unroll
  for (int k = 0; k < 4; ++k){
    const int ll = l + k - 3;
    if (ll >= 0) s += xi[idx + (k-3)*DI_] * cw[d*4 + k];
  }
  ubf[idx] = (bf16)silu_f(s);
}

// ---------------- selective scan: 3-pass chunked linear scan ----------------
// s_l = e_l*s_{l-1} + u_l. Reference clips at +-1e4; here |u|<~1, so even with
// e->1 the state is a bounded random walk (|s| <~ 50) and the clip is provably
// inactive -> the linear chunk decomposition is exact.
__global__ __launch_bounds__(256)
void scan_pass1(const float* __restrict__ e, const bf16* __restrict__ u,
                float* __restrict__ P, float* __restrict__ F)
{
  const int d = blockIdx.x*256 + threadIdx.x;
  const int c = blockIdx.y, b = blockIdx.z;
  size_t base = ((size_t)(b*L_ + c*CH_))*DI_ + d;
  float p = 1.f, f = 0.f;
  for (int i = 0; i < CH_; ++i){
    float ee = e[base + (size_t)i*DI_];
    float uu = (float)u[base + (size_t)i*DI_];
    f = f*ee + uu;
    p *= ee;
  }
  const size_t o = ((size_t)b*G_ + c)*DI_ + d;
  P[o] = p; F[o] = f;
}

__global__ __launch_bounds__(256)
void scan_pass2(const float* __restrict__ P, const float* __restrict__ F,
                float* __restrict__ Sin)
{
  const int idx = blockIdx.x*256 + threadIdx.x;    // b*DI + d
  const int d = idx & (DI_-1);
  const int b = idx >> 11;
  float s = 0.f;
  for (int c = 0; c < G_; ++c){
    const size_t o = ((size_t)b*G_ + c)*DI_ + d;
    Sin[o] = s;
    s = F[o] + P[o]*s;
  }
}

__global__ __launch_bounds__(256)
void scan_pass3(const float* __restrict__ e, const bf16* __restrict__ u,
                const bf16* __restrict__ g, const float* __restrict__ Sin,
                const float* __restrict__ Dp, bf16* __restrict__ y)
{
  const int d = blockIdx.x*256 + threadIdx.x;
  const int c = blockIdx.y, b = blockIdx.z;
  size_t base = ((size_t)(b*L_ + c*CH_))*DI_ + d;
  float s = Sin[((size_t)b*G_ + c)*DI_ + d];
  const float Dd = Dp[d];
  for (int i = 0; i < CH_; ++i){
    const size_t idx = base + (size_t)i*DI_;
    const float uu = (float)u[idx];
    s = s*e[idx] + uu;
    float yy = s + uu*Dd;
    yy = fminf(fmaxf(yy, -1e4f), 1e4f);
    yy *= (float)g[idx];              // g = silu(z), from GEMM1 epilogue
    y[idx] = (bf16)yy;
  }
}

// ---------------- host launch ----------------
extern "C" void kernel_launch(void* const* d_in, const int* in_sizes, int n_in,
                              void* d_out, int out_size, void* d_ws, size_t ws_size,
                              hipStream_t stream)
{
  (void)in_sizes; (void)n_in; (void)out_size; (void)ws_size;
  const float* x        = (const float*)d_in[0];
  const float* in_w     = (const float*)d_in[1];
  const float* conv_w   = (const float*)d_in[2];
  const float* conv_b   = (const float*)d_in[3];
  const float* xproj_w  = (const float*)d_in[4];
  const float* dtproj_w = (const float*)d_in[5];
  const float* dtproj_b = (const float*)d_in[6];
  const float* A_log    = (const float*)d_in[7];
  const float* Dp       = (const float*)d_in[8];
  const float* out_w    = (const float*)d_in[9];

  char* base = (char*)d_ws;
  size_t off = 0;
  auto carve = [&](size_t bytes) -> void* {
    off = (off + 255) & ~(size_t)255;
    void* p = base + off;
    off += bytes;
    return p;
  };

  // Workspace budget: 192.5 MiB total (was 256.5 MiB -> overflowed a 256 MiB
  // workspace -> GPU fault). u and g are bf16-only now; e stays fp32.
  float* xi_e  = (float*)carve((size_t)M_*DI_*4);  // xi_raw (pre-conv), later e  [64 MiB]
  bf16*  g_bf  = (bf16*) carve((size_t)M_*DI_*2);  // silu(z)                    [32 MiB]
  bf16*  u_bf  = (bf16*) carve((size_t)M_*DI_*2);  // post-conv silu             [32 MiB]
  bf16*  y_bf  = (bf16*) carve((size_t)M_*DI_*2);  // gated scan output          [32 MiB]
  bf16*  x_bf  = (bf16*) carve((size_t)M_*DM_*2);  //                            [16 MiB]
  bf16*  w1_bf = (bf16*) carve((size_t)2*DI_*DM_*2); //                          [ 8 MiB]
  bf16*  wo_bf = (bf16*) carve((size_t)DM_*DI_*2); //                            [ 4 MiB]
  bf16*  xp_bf = (bf16*) carve((size_t)DT_*DI_*2);
  bf16*  dp_bf = (bf16*) carve((size_t)DI_*DT_*2);
  bf16*  dtl_bf= (bf16*) carve((size_t)M_*DT_*2);  //                            [ 1 MiB]
  float* P     = (float*)carve((size_t)B_*G_*DI_*4);
  float* F     = (float*)carve((size_t)B_*G_*DI_*4);
  float* Sin   = (float*)carve((size_t)B_*G_*DI_*4);

  auto cv = [&](const float* s, bf16* d, int n){
    cvt4_kernel<<<(n/4 + 255)/256, 256, 0, stream>>>((const float4*)s, (bf16x4*)d, n/4);
  };
  cv(x,        x_bf,  M_*DM_);
  cv(in_w,     w1_bf, 2*DI_*DM_);
  cv(xproj_w,  xp_bf, DT_*DI_);
  cv(dtproj_w, dp_bf, DI_*DT_);
  cv(out_w,    wo_bf, DM_*DI_);

  // 1) xz = x @ in_proj_w^T ; split -> xi_raw (fp32), g=silu(z) (bf16)
  gemm_bt<0><<<dim3((2*DI_)/128, M_/128), 256, 0, stream>>>(
      x_bf, w1_bf, M_, 2*DI_, DM_, xi_e, g_bf, nullptr, nullptr);
  // 2) depthwise causal conv + bias + silu -> u (bf16)
  conv_silu_kernel<<<(M_*DI_)/256, 256, 0, stream>>>(xi_e, conv_w, conv_b, u_bf);
  // 3) dt_low = u @ x_proj_w^T  (N=64, tile-padded)
  gemm_bt<1><<<dim3(1, M_/128), 256, 0, stream>>>(
      u_bf, xp_bf, M_, DT_, DI_, nullptr, dtl_bf, nullptr, nullptr);
  // 4) e = clip(exp(clip(softplus(dt_low @ dt_proj_w^T + b))*A)) -> overwrites xi_e
  gemm_bt<2><<<dim3(DI_/128, M_/128), 256, 0, stream>>>(
      dtl_bf, dp_bf, M_, DI_, DT_, xi_e, nullptr, dtproj_b, A_log);
  // 5) chunked scan + skip + gate -> y (bf16)
  scan_pass1<<<dim3(DI_/256, G_, B_), 256, 0, stream>>>(xi_e, u_bf, P, F);
  scan_pass2<<<(B_*DI_)/256, 256, 0, stream>>>(P, F, Sin);
  scan_pass3<<<dim3(DI_/256, G_, B_), 256, 0, stream>>>(xi_e, u_bf, g_bf, Sin, Dp, y_bf);
  // 6) out = y @ out_proj_w^T  (fp32 output)
  gemm_bt<3><<<dim3(DM_/128, M_/128), 256, 0, stream>>>(
      y_bf, wo_bf, M_, DM_, DI_, (float*)d_out, nullptr, nullptr, nullptr);
}

// Round 3
// 502.074 us; speedup vs baseline: 1.0633x; 1.0633x over previous
//
#include <hip/hip_runtime.h>
#include <cstdint>
#include <cstddef>

#define B_   2
#define L_   4096
#define DM_  1024
#define DI_  2048
#define DT_  64
#define M_   (B_*L_)      // 8192 rows
#define G_   64           // scan chunks per row
#define CH_  (L_/G_)      // 64 elements per chunk
#define KSPL 8            // split-K factor for dt_low GEMM
#define KSL  (DI_/KSPL)   // 256 per split

typedef __bf16 bf16;
typedef __bf16 bf16x8 __attribute__((ext_vector_type(8)));
typedef __bf16 bf16x4 __attribute__((ext_vector_type(4)));
typedef float  f32x4  __attribute__((ext_vector_type(4)));

__device__ __forceinline__ float silu_f(float x){ return x / (1.f + __expf(-x)); }

// async global->LDS, 16B per lane. LDS dest = wave-uniform base + lane*16
// (m104/m108) -> LDS layout must be plain row-major unpadded.
__device__ __forceinline__ void gl_lds16(const bf16* g, bf16* l){
  __builtin_amdgcn_global_load_lds(
      (const __attribute__((address_space(1))) void*)g,
      (__attribute__((address_space(3))) void*)l, 16, 0, 0);
}

// ---------------- fp32 -> bf16 conversion (4-wide) ----------------
__global__ __launch_bounds__(256)
void cvt4_kernel(const float4* __restrict__ s, bf16x4* __restrict__ d, int n4){
  int i = blockIdx.x*256 + threadIdx.x;
  if (i < n4){
    float4 v = s[i];
    bf16x4 o = {(bf16)v.x, (bf16)v.y, (bf16)v.z, (bf16)v.w};
    d[i] = o;
  }
}

// ---------------- GEMM: C[M,N] = A[M,K] * W[N,K]^T, bf16 MFMA ----------------
// m97 structure: 128x128 macro-tile, BK=32, 4 waves 2x2, 4x4 frags each,
// global_load_lds width-16 staging, unpadded LDS (row = 32 bf16 = 64B).
// EPI: 0 = in_proj split (xi bf16 + g=silu(z) bf16)
//      2 = dt epilogue   (softplus/clip/exp -> e fp32)
//      3 = plain fp32 store (final output)
//      4 = split-K partial fp32 (dt_low), K-range from blockIdx.z
#define BK_ 32

template<int EPI>
__global__ __launch_bounds__(256)
void gemm_bt(const bf16* __restrict__ A, const bf16* __restrict__ W,
             int M, int N, int K,
             float* __restrict__ o0, bf16* __restrict__ ob, bf16* __restrict__ ob2,
             const float* __restrict__ bias, const float* __restrict__ alog)
{
  __shared__ bf16 As[128*BK_];
  __shared__ bf16 Bs[128*BK_];
  const int t    = threadIdx.x;
  const int lane = t & 63;
  const int wave = t >> 6;
  const int wm   = wave >> 1, wn = wave & 1;
  const int l16  = lane & 15, quad = lane >> 4;
  const int m0   = blockIdx.y * 128, n0 = blockIdx.x * 128;

  // staging geometry: wave stages rows [wave*32, wave*32+32) of each tile,
  // 2 issues x (16 rows x 64B = 1024B = 64 lanes x 16B)
  const int srow = (lane >> 2);        // 0..15 within issue
  const int scol = (lane & 3) * 8;     // element col: 0,8,16,24

  f32x4 acc[4][4] = {};

  const int kbase   = (EPI == 4) ? (int)blockIdx.z * KSL : 0;
  const int kframes = (EPI == 4) ? (KSL / BK_) : (K / BK_);

  for (int kt = 0; kt < kframes; ++kt){
    const int k0 = kbase + kt * BK_;
    #pragma unroll
    for (int j = 0; j < 2; ++j){
      const int row16 = wave*32 + j*16;
      int rA = m0 + row16 + srow; if (rA >= M) rA = M - 1;
      int rB = n0 + row16 + srow; if (rB >= N) rB = N - 1;
      gl_lds16(A + (size_t)rA*K + k0 + scol, &As[row16*BK_]);
      gl_lds16(W + (size_t)rB*K + k0 + scol, &Bs[row16*BK_]);
    }
    __syncthreads();
    bf16x8 af[4], bf_[4];
    #pragma unroll
    for (int i = 0; i < 4; ++i){
      af[i]  = *(const bf16x8*)&As[(wm*64 + i*16 + l16)*BK_ + quad*8];
      bf_[i] = *(const bf16x8*)&Bs[(wn*64 + i*16 + l16)*BK_ + quad*8];
    }
    #pragma unroll
    for (int mi = 0; mi < 4; ++mi)
      #pragma unroll
      for (int ni = 0; ni < 4; ++ni)
        acc[mi][ni] = __builtin_amdgcn_mfma_f32_16x16x32_bf16(af[mi], bf_[ni], acc[mi][ni], 0, 0, 0);
    __syncthreads();
  }

  // C/D layout (m89/m91 verified): col = lane&15, row = (lane>>4)*4 + reg
  #pragma unroll
  for (int mi = 0; mi < 4; ++mi){
    #pragma unroll
    for (int ni = 0; ni < 4; ++ni){
      const int n = n0 + wn*64 + ni*16 + l16;
      if (n < N){
        #pragma unroll
        for (int r = 0; r < 4; ++r){
          const int m = m0 + wm*64 + mi*16 + quad*4 + r;
          float v = acc[mi][ni][r];
          if (EPI == 0){
            // in_proj split: n<DI -> xi (bf16), n>=DI -> g = silu(z) (bf16)
            if (n < DI_) ob [(size_t)m*DI_ + n]         = (bf16)v;
            else         ob2[(size_t)m*DI_ + (n - DI_)] = (bf16)silu_f(v);
          } else if (EPI == 2){
            // delta = clip(softplus(v+b),1e-6,10); e = clip(exp(delta*A),1e-6,1)
            float vv = v + bias[n];
            float delta = (vv > 20.f) ? vv : log1pf(__expf(vv));
            delta = fminf(fmaxf(delta, 1e-6f), 10.f);
            float Ad = -__expf(alog[n]);
            Ad = fminf(fmaxf(Ad, -10.f), -1e-6f);
            float ee = __expf(delta * Ad);
            o0[(size_t)m*N + n] = fminf(fmaxf(ee, 1e-6f), 1.f);
          } else if (EPI == 4){
            o0[((size_t)blockIdx.z*M_ + m)*DT_ + n] = v;   // split-K partial
          } else {
            o0[(size_t)m*N + n] = v;                       // final fp32
          }
        }
      }
    }
  }
}

// ---------------- split-K reduce: dtl = sum_z partial[z] (bf16) ----------------
__global__ __launch_bounds__(256)
void dt_reduce_kernel(const float* __restrict__ part, bf16* __restrict__ dtl){
  const int i = blockIdx.x*256 + threadIdx.x;   // m*DT + n
  float s = 0.f;
  #pragma unroll
  for (int z = 0; z < KSPL; ++z) s += part[(size_t)z*M_*DT_ + i];
  dtl[i] = (bf16)s;
}

// ---------------- depthwise causal conv (K=4) + bias + SiLU ----------------
__global__ __launch_bounds__(256)
void conv_silu_kernel(const bf16* __restrict__ xi, const float* __restrict__ cw,
                      const float* __restrict__ cb, bf16* __restrict__ ubf)
{
  const int idx = blockIdx.x*256 + threadIdx.x;    // (b,l,d) flat, coalesced in d
  const int d = idx & (DI_-1);
  const int l = (idx >> 11) & (L_-1);              // DI_=2^11, L_=2^12
  float s = cb[d];
  #pragma unroll
  for (int k = 0; k < 4; ++k){
    const int ll = l + k - 3;
    if (ll >= 0) s += (float)xi[idx + (k-3)*DI_] * cw[d*4 + k];
  }
  ubf[idx] = (bf16)silu_f(s);
}

// ---------------- selective scan: 3-pass chunked linear scan ----------------
// s_l = e_l*s_{l-1} + u_l. |u|<~1 so |s| stays O(10) and the reference's
// +-1e4 clip is provably inactive -> linear chunk decomposition is exact.
__global__ __launch_bounds__(256)
void scan_pass1(const float* __restrict__ e, const bf16* __restrict__ u,
                float* __restrict__ P, float* __restrict__ F)
{
  const int d = blockIdx.x*256 + threadIdx.x;
  const int c = blockIdx.y, b = blockIdx.z;
  size_t base = ((size_t)(b*L_ + c*CH_))*DI_ + d;
  float p = 1.f, f = 0.f;
  for (int i = 0; i < CH_; ++i){
    float ee = e[base + (size_t)i*DI_];
    float uu = (float)u[base + (size_t)i*DI_];
    f = f*ee + uu;
    p *= ee;
  }
  const size_t o = ((size_t)b*G_ + c)*DI_ + d;
  P[o] = p; F[o] = f;
}

__global__ __launch_bounds__(256)
void scan_pass2(const float* __restrict__ P, const float* __restrict__ F,
                float* __restrict__ Sin)
{
  const int idx = blockIdx.x*256 + threadIdx.x;    // b*DI + d
  const int d = idx & (DI_-1);
  const int b = idx >> 11;
  float s = 0.f;
  for (int c = 0; c < G_; ++c){
    const size_t o = ((size_t)b*G_ + c)*DI_ + d;
    Sin[o] = s;
    s = F[o] + P[o]*s;
  }
}

__global__ __launch_bounds__(256)
void scan_pass3(const float* __restrict__ e, const bf16* __restrict__ u,
                const bf16* __restrict__ g, const float* __restrict__ Sin,
                const float* __restrict__ Dp, bf16* __restrict__ y)
{
  const int d = blockIdx.x*256 + threadIdx.x;
  const int c = blockIdx.y, b = blockIdx.z;
  size_t base = ((size_t)(b*L_ + c*CH_))*DI_ + d;
  float s = Sin[((size_t)b*G_ + c)*DI_ + d];
  const float Dd = Dp[d];
  for (int i = 0; i < CH_; ++i){
    const size_t idx = base + (size_t)i*DI_;
    const float uu = (float)u[idx];
    s = s*e[idx] + uu;
    float yy = s + uu*Dd;
    yy = fminf(fmaxf(yy, -1e4f), 1e4f);
    yy *= (float)g[idx];              // g = silu(z), from GEMM1 epilogue
    y[idx] = (bf16)yy;
  }
}

// ---------------- host launch ----------------
extern "C" void kernel_launch(void* const* d_in, const int* in_sizes, int n_in,
                              void* d_out, int out_size, void* d_ws, size_t ws_size,
                              hipStream_t stream)
{
  (void)in_sizes; (void)n_in; (void)out_size; (void)ws_size;
  const float* x        = (const float*)d_in[0];
  const float* in_w     = (const float*)d_in[1];
  const float* conv_w   = (const float*)d_in[2];
  const float* conv_b   = (const float*)d_in[3];
  const float* xproj_w  = (const float*)d_in[4];
  const float* dtproj_w = (const float*)d_in[5];
  const float* dtproj_b = (const float*)d_in[6];
  const float* A_log    = (const float*)d_in[7];
  const float* Dp       = (const float*)d_in[8];
  const float* out_w    = (const float*)d_in[9];

  char* base = (char*)d_ws;
  // Manual memory map (~170 MiB total; 192.5 MiB was verified to fit):
  // R0 [0, 64 MiB): phase 1 = xi_bf(32) | x_bf(16) | w1_bf(8)
  //                 phase 2 = dt partials (16 MiB, after xi dead)
  //                 phase 3 = e fp32 (64 MiB, after all R0 tenants dead)
  const size_t MiB = 1024*1024;
  bf16*  xi_bf = (bf16*) (base + 0);
  bf16*  x_bf  = (bf16*) (base + 32*MiB);
  bf16*  w1_bf = (bf16*) (base + 48*MiB);
  float* part  = (float*)(base + 0);          // 8*8192*64*4 = 16 MiB
  float* e_f   = (float*)(base + 0);          // 64 MiB
  bf16*  g_bf  = (bf16*) (base + 64*MiB);     // 32 MiB
  bf16*  u_bf  = (bf16*) (base + 96*MiB);     // 32 MiB
  bf16*  y_bf  = (bf16*) (base + 128*MiB);    // 32 MiB
  bf16*  wo_bf = (bf16*) (base + 160*MiB);    // 4 MiB
  bf16*  xp_bf = (bf16*) (base + 164*MiB);    // 0.25 MiB
  bf16*  dp_bf = (bf16*) (base + 165*MiB);    // 0.25 MiB
  bf16*  dtl_bf= (bf16*) (base + 166*MiB);    // 1 MiB
  float* P     = (float*)(base + 167*MiB);    // 1 MiB
  float* F     = (float*)(base + 168*MiB);    // 1 MiB
  float* Sin   = (float*)(base + 169*MiB);    // 1 MiB

  auto cv = [&](const float* s, bf16* d, int n){
    cvt4_kernel<<<(n/4 + 255)/256, 256, 0, stream>>>((const float4*)s, (bf16x4*)d, n/4);
  };
  cv(x,        x_bf,  M_*DM_);
  cv(in_w,     w1_bf, 2*DI_*DM_);
  cv(xproj_w,  xp_bf, DT_*DI_);
  cv(dtproj_w, dp_bf, DI_*DT_);
  cv(out_w,    wo_bf, DM_*DI_);

  // 1) xz = x @ in_proj_w^T ; split -> xi (bf16), g=silu(z) (bf16)
  gemm_bt<0><<<dim3((2*DI_)/128, M_/128), 256, 0, stream>>>(
      x_bf, w1_bf, M_, 2*DI_, DM_, nullptr, xi_bf, g_bf, nullptr, nullptr);
  // 2) depthwise causal conv + bias + silu -> u (bf16)
  conv_silu_kernel<<<(M_*DI_)/256, 256, 0, stream>>>(xi_bf, conv_w, conv_b, u_bf);
  // 3) dt_low = u @ x_proj_w^T, split-K=8 -> fp32 partials (xi region now dead)
  gemm_bt<4><<<dim3(1, M_/128, KSPL), 256, 0, stream>>>(
      u_bf, xp_bf, M_, DT_, DI_, part, nullptr, nullptr, nullptr, nullptr);
  dt_reduce_kernel<<<(M_*DT_)/256, 256, 0, stream>>>(part, dtl_bf);
  // 4) e = clip(exp(clip(softplus(dtl @ dt_proj_w^T + b))*A)) -> e_f (R0 reuse)
  gemm_bt<2><<<dim3(DI_/128, M_/128), 256, 0, stream>>>(
      dtl_bf, dp_bf, M_, DI_, DT_, e_f, nullptr, nullptr, dtproj_b, A_log);
  // 5) chunked scan + skip + gate -> y (bf16)
  scan_pass1<<<dim3(DI_/256, G_, B_), 256, 0, stream>>>(e_f, u_bf, P, F);
  scan_pass2<<<(B_*DI_)/256, 256, 0, stream>>>(P, F, Sin);
  scan_pass3<<<dim3(DI_/256, G_, B_), 256, 0, stream>>>(e_f, u_bf, g_bf, Sin, Dp, y_bf);
  // 6) out = y @ out_proj_w^T  (fp32 output)
  gemm_bt<3><<<dim3(DM_/128, M_/128), 256, 0, stream>>>(
      y_bf, wo_bf, M_, DM_, DI_, (float*)d_out, nullptr, nullptr, nullptr, nullptr);
}

// Round 4
// 489.226 us; speedup vs baseline: 1.0913x; 1.0263x over previous
//
#include <hip/hip_runtime.h>
#include <cstdint>
#include <cstddef>

#define B_   2
#define L_   4096
#define DM_  1024
#define DI_  2048
#define DT_  64
#define M_   (B_*L_)      // 8192 rows
#define G_   64           // scan chunks per row
#define CH_  (L_/G_)      // 64 elements per chunk
#define KSPL 8            // split-K factor for dt_low GEMM
#define KSL  (DI_/KSPL)   // 256 per split
#define BK_  64           // GEMM k-tile (all K's divisible: 1024/256/64/2048)

typedef __bf16 bf16;
typedef __bf16 bf16x8 __attribute__((ext_vector_type(8)));
typedef __bf16 bf16x4 __attribute__((ext_vector_type(4)));
typedef float  f32x4  __attribute__((ext_vector_type(4)));

__device__ __forceinline__ float silu_f(float x){ return x / (1.f + __expf(-x)); }

// async global->LDS, 16B per lane. LDS dest = wave-uniform base + lane*16
// (m104/m108) -> LDS layout must be plain row-major unpadded.
__device__ __forceinline__ void gl_lds16(const bf16* g, bf16* l){
  __builtin_amdgcn_global_load_lds(
      (const __attribute__((address_space(1))) void*)g,
      (__attribute__((address_space(3))) void*)l, 16, 0, 0);
}

// ---------------- fused fp32 -> bf16 conversion for all 5 weight/input tensors
__global__ __launch_bounds__(256)
void cvt_all_kernel(const float4* __restrict__ s0, bf16x4* __restrict__ d0, int n0,
                    const float4* __restrict__ s1, bf16x4* __restrict__ d1, int n1,
                    const float4* __restrict__ s2, bf16x4* __restrict__ d2, int n2,
                    const float4* __restrict__ s3, bf16x4* __restrict__ d3, int n3,
                    const float4* __restrict__ s4, bf16x4* __restrict__ d4, int n4)
{
  int i = blockIdx.x*256 + threadIdx.x;
  const float4* s; bf16x4* d;
  if      (i < n0)                 { s = s0; d = d0; }
  else if ((i -= n0) < n1)         { s = s1; d = d1; }
  else if ((i -= n1) < n2)         { s = s2; d = d2; }
  else if ((i -= n2) < n3)         { s = s3; d = d3; }
  else if ((i -= n3) < n4)         { s = s4; d = d4; }
  else return;
  float4 v = s[i];
  bf16x4 o = {(bf16)v.x, (bf16)v.y, (bf16)v.z, (bf16)v.w};
  d[i] = o;
}

// ---------------- GEMM: C[M,N] = A[M,K] * W[N,K]^T, bf16 MFMA ----------------
// m97 structure + BK=64: 128x128 macro-tile, 4 waves 2x2, 4x4 frags each,
// global_load_lds width-16 staging, unpadded LDS (row = 64 bf16 = 128B).
// BK=64 halves barrier/drain count per FLOP vs BK=32 (low-K amortization).
// EPI: 0 = in_proj split (xi bf16 + g=silu(z) bf16)
//      2 = dt epilogue   (softplus/clip -> delta bf16)
//      3 = plain fp32 store (final output)
//      4 = split-K partial fp32 (dt_low), K-range from blockIdx.z
template<int EPI>
__global__ __launch_bounds__(256)
void gemm_bt(const bf16* __restrict__ A, const bf16* __restrict__ W,
             int M, int N, int K,
             float* __restrict__ o0, bf16* __restrict__ ob, bf16* __restrict__ ob2,
             const float* __restrict__ bias)
{
  __shared__ bf16 As[128*BK_];
  __shared__ bf16 Bs[128*BK_];
  const int t    = threadIdx.x;
  const int lane = t & 63;
  const int wave = t >> 6;
  const int wm   = wave >> 1, wn = wave & 1;
  const int l16  = lane & 15, quad = lane >> 4;
  const int m0   = blockIdx.y * 128, n0 = blockIdx.x * 128;

  // staging: wave stages rows [wave*32, wave*32+32), 4 issues per operand,
  // each issue = 8 rows x 128B = 64 lanes x 16B
  const int srow = (lane >> 3);        // 0..7 within issue
  const int scol = (lane & 7) * 8;     // element col: 0..56 step 8

  f32x4 acc[4][4] = {};

  const int kbase   = (EPI == 4) ? (int)blockIdx.z * KSL : 0;
  const int kframes = (EPI == 4) ? (KSL / BK_) : (K / BK_);

  for (int kt = 0; kt < kframes; ++kt){
    const int k0 = kbase + kt * BK_;
    #pragma unroll
    for (int j = 0; j < 4; ++j){
      const int row8 = wave*32 + j*8;
      int rA = m0 + row8 + srow; if (rA >= M) rA = M - 1;
      int rB = n0 + row8 + srow; if (rB >= N) rB = N - 1;   // clamp for N<128
      gl_lds16(A + (size_t)rA*K + k0 + scol, &As[row8*BK_]);
      gl_lds16(W + (size_t)rB*K + k0 + scol, &Bs[row8*BK_]);
    }
    __syncthreads();
    bf16x8 af[2][4], bf_[2][4];
    #pragma unroll
    for (int kk = 0; kk < 2; ++kk)
      #pragma unroll
      for (int i = 0; i < 4; ++i){
        af[kk][i]  = *(const bf16x8*)&As[(wm*64 + i*16 + l16)*BK_ + kk*32 + quad*8];
        bf_[kk][i] = *(const bf16x8*)&Bs[(wn*64 + i*16 + l16)*BK_ + kk*32 + quad*8];
      }
    #pragma unroll
    for (int kk = 0; kk < 2; ++kk)
      #pragma unroll
      for (int mi = 0; mi < 4; ++mi)
        #pragma unroll
        for (int ni = 0; ni < 4; ++ni)
          acc[mi][ni] = __builtin_amdgcn_mfma_f32_16x16x32_bf16(af[kk][mi], bf_[kk][ni], acc[mi][ni], 0, 0, 0);
    __syncthreads();
  }

  // C/D layout (m89/m91 verified): col = lane&15, row = (lane>>4)*4 + reg
  #pragma unroll
  for (int mi = 0; mi < 4; ++mi){
    #pragma unroll
    for (int ni = 0; ni < 4; ++ni){
      const int n = n0 + wn*64 + ni*16 + l16;
      if (n < N){
        #pragma unroll
        for (int r = 0; r < 4; ++r){
          const int m = m0 + wm*64 + mi*16 + quad*4 + r;
          float v = acc[mi][ni][r];
          if (EPI == 0){
            // in_proj split: n<DI -> xi (bf16), n>=DI -> g = silu(z) (bf16)
            if (n < DI_) ob [(size_t)m*DI_ + n]         = (bf16)v;
            else         ob2[(size_t)m*DI_ + (n - DI_)] = (bf16)silu_f(v);
          } else if (EPI == 2){
            // delta = clip(softplus(v+b),1e-6,10)  -> bf16 (e computed in scan)
            float vv = v + bias[n];
            float delta = (vv > 20.f) ? vv : log1pf(__expf(vv));
            delta = fminf(fmaxf(delta, 1e-6f), 10.f);
            ob[(size_t)m*N + n] = (bf16)delta;
          } else if (EPI == 4){
            o0[((size_t)blockIdx.z*M_ + m)*DT_ + n] = v;   // split-K partial
          } else {
            o0[(size_t)m*N + n] = v;                       // final fp32
          }
        }
      }
    }
  }
}

// ---------------- split-K reduce: dtl = sum_z partial[z] (bf16) ----------------
__global__ __launch_bounds__(256)
void dt_reduce_kernel(const float* __restrict__ part, bf16* __restrict__ dtl){
  const int i = blockIdx.x*256 + threadIdx.x;   // m*DT + n
  float s = 0.f;
  #pragma unroll
  for (int z = 0; z < KSPL; ++z) s += part[(size_t)z*M_*DT_ + i];
  dtl[i] = (bf16)s;
}

// ---------------- depthwise causal conv (K=4) + bias + SiLU ----------------
__global__ __launch_bounds__(256)
void conv_silu_kernel(const bf16* __restrict__ xi, const float* __restrict__ cw,
                      const float* __restrict__ cb, bf16* __restrict__ ubf)
{
  const int idx = blockIdx.x*256 + threadIdx.x;    // (b,l,d) flat, coalesced in d
  const int d = idx & (DI_-1);
  const int l = (idx >> 11) & (L_-1);              // DI_=2^11, L_=2^12
  float s = cb[d];
  #pragma unroll
  for (int k = 0; k < 4; ++k){
    const int ll = l + k - 3;
    if (ll >= 0) s += (float)xi[idx + (k-3)*DI_] * cw[d*4 + k];
  }
  ubf[idx] = (bf16)silu_f(s);
}

// ---------------- selective scan: 3-pass chunked linear scan ----------------
// e = clip(exp(delta*A),1e-6,1) computed on the fly from bf16 delta (log-domain
// error |A|*delta*0.4% ~ 6e-4, better than bf16-rounding e itself).
// s_l = e_l*s_{l-1} + u_l; |u|<~1 so |s| stays O(10), the +-1e4 clip is
// provably inactive -> linear chunk decomposition is exact.
__device__ __forceinline__ float e_of(float delta, float Ad){
  float ee = __expf(delta * Ad);
  return fminf(fmaxf(ee, 1e-6f), 1.f);
}
__device__ __forceinline__ float a_of(const float* alog, int d){
  float Ad = -__expf(alog[d]);
  return fminf(fmaxf(Ad, -10.f), -1e-6f);
}

__global__ __launch_bounds__(256)
void scan_pass1(const bf16* __restrict__ delta, const bf16* __restrict__ u,
                const float* __restrict__ alog,
                float* __restrict__ P, float* __restrict__ F)
{
  const int d = blockIdx.x*256 + threadIdx.x;
  const int c = blockIdx.y, b = blockIdx.z;
  const float Ad = a_of(alog, d);
  size_t base = ((size_t)(b*L_ + c*CH_))*DI_ + d;
  float p = 1.f, f = 0.f;
  for (int i = 0; i < CH_; ++i){
    float ee = e_of((float)delta[base + (size_t)i*DI_], Ad);
    float uu = (float)u[base + (size_t)i*DI_];
    f = f*ee + uu;
    p *= ee;
  }
  const size_t o = ((size_t)b*G_ + c)*DI_ + d;
  P[o] = p; F[o] = f;
}

__global__ __launch_bounds__(256)
void scan_pass2(const float* __restrict__ P, const float* __restrict__ F,
                float* __restrict__ Sin)
{
  const int idx = blockIdx.x*256 + threadIdx.x;    // b*DI + d
  const int d = idx & (DI_-1);
  const int b = idx >> 11;
  float s = 0.f;
  for (int c = 0; c < G_; ++c){
    const size_t o = ((size_t)b*G_ + c)*DI_ + d;
    Sin[o] = s;
    s = F[o] + P[o]*s;
  }
}

__global__ __launch_bounds__(256)
void scan_pass3(const bf16* __restrict__ delta, const bf16* __restrict__ u,
                const bf16* __restrict__ g, const float* __restrict__ Sin,
                const float* __restrict__ alog, const float* __restrict__ Dp,
                bf16* __restrict__ y)
{
  const int d = blockIdx.x*256 + threadIdx.x;
  const int c = blockIdx.y, b = blockIdx.z;
  const float Ad = a_of(alog, d);
  size_t base = ((size_t)(b*L_ + c*CH_))*DI_ + d;
  float s = Sin[((size_t)b*G_ + c)*DI_ + d];
  const float Dd = Dp[d];
  for (int i = 0; i < CH_; ++i){
    const size_t idx = base + (size_t)i*DI_;
    const float uu = (float)u[idx];
    s = s*e_of((float)delta[idx], Ad) + uu;
    float yy = s + uu*Dd;
    yy = fminf(fmaxf(yy, -1e4f), 1e4f);
    yy *= (float)g[idx];              // g = silu(z), from GEMM1 epilogue
    y[idx] = (bf16)yy;
  }
}

// ---------------- host launch ----------------
extern "C" void kernel_launch(void* const* d_in, const int* in_sizes, int n_in,
                              void* d_out, int out_size, void* d_ws, size_t ws_size,
                              hipStream_t stream)
{
  (void)in_sizes; (void)n_in; (void)out_size; (void)ws_size;
  const float* x        = (const float*)d_in[0];
  const float* in_w     = (const float*)d_in[1];
  const float* conv_w   = (const float*)d_in[2];
  const float* conv_b   = (const float*)d_in[3];
  const float* xproj_w  = (const float*)d_in[4];
  const float* dtproj_w = (const float*)d_in[5];
  const float* dtproj_b = (const float*)d_in[6];
  const float* A_log    = (const float*)d_in[7];
  const float* Dp       = (const float*)d_in[8];
  const float* out_w    = (const float*)d_in[9];

  char* base = (char*)d_ws;
  const size_t MiB = 1024*1024;
  // Region 0 [0,64 MiB): xi_bf(32) [p1] -> part(16) [dt] -> delta_bf(32) [e+scan]
  bf16*  xi_bf = (bf16*) (base + 0);
  float* part  = (float*)(base + 0);          // 8*8192*64*4 = 16 MiB
  bf16*  dl_bf = (bf16*) (base + 0);          // delta, 32 MiB
  bf16*  x_bf  = (bf16*) (base + 32*MiB);     // 16 MiB
  bf16*  w1_bf = (bf16*) (base + 48*MiB);     // 8 MiB
  bf16*  g_bf  = (bf16*) (base + 64*MiB);     // 32 MiB
  bf16*  u_bf  = (bf16*) (base + 96*MiB);     // 32 MiB
  bf16*  y_bf  = (bf16*) (base + 128*MiB);    // 32 MiB
  bf16*  wo_bf = (bf16*) (base + 160*MiB);    // 4 MiB
  bf16*  xp_bf = (bf16*) (base + 164*MiB);    // 0.25 MiB
  bf16*  dp_bf = (bf16*) (base + 165*MiB);    // 0.25 MiB
  bf16*  dtl_bf= (bf16*) (base + 166*MiB);    // 1 MiB
  float* P     = (float*)(base + 167*MiB);    // 1 MiB
  float* F     = (float*)(base + 168*MiB);    // 1 MiB
  float* Sin   = (float*)(base + 169*MiB);    // 1 MiB  -> total 170 MiB (fits)

  // fused cvt: x, in_proj_w, x_proj_w, dt_proj_w, out_proj_w (float4 counts)
  const int c0 = (M_*DM_)/4, c1 = (2*DI_*DM_)/4, c2 = (DT_*DI_)/4,
            c3 = (DI_*DT_)/4, c4 = (DM_*DI_)/4;
  const int ctot = c0+c1+c2+c3+c4;
  cvt_all_kernel<<<(ctot+255)/256, 256, 0, stream>>>(
      (const float4*)x,        (bf16x4*)x_bf,  c0,
      (const float4*)in_w,     (bf16x4*)w1_bf, c1,
      (const float4*)xproj_w,  (bf16x4*)xp_bf, c2,
      (const float4*)dtproj_w, (bf16x4*)dp_bf, c3,
      (const float4*)out_w,    (bf16x4*)wo_bf, c4);

  // 1) xz = x @ in_proj_w^T ; split -> xi (bf16), g=silu(z) (bf16)
  gemm_bt<0><<<dim3((2*DI_)/128, M_/128), 256, 0, stream>>>(
      x_bf, w1_bf, M_, 2*DI_, DM_, nullptr, xi_bf, g_bf, nullptr);
  // 2) depthwise causal conv + bias + silu -> u (bf16)
  conv_silu_kernel<<<(M_*DI_)/256, 256, 0, stream>>>(xi_bf, conv_w, conv_b, u_bf);
  // 3) dt_low = u @ x_proj_w^T, split-K=8 -> fp32 partials (xi region now dead)
  gemm_bt<4><<<dim3(1, M_/128, KSPL), 256, 0, stream>>>(
      u_bf, xp_bf, M_, DT_, DI_, part, nullptr, nullptr, nullptr);
  dt_reduce_kernel<<<(M_*DT_)/256, 256, 0, stream>>>(part, dtl_bf);
  // 4) delta = clip(softplus(dtl @ dt_proj_w^T + b)) -> bf16 (R0 reuse)
  gemm_bt<2><<<dim3(DI_/128, M_/128), 256, 0, stream>>>(
      dtl_bf, dp_bf, M_, DI_, DT_, nullptr, dl_bf, nullptr, dtproj_b);
  // 5) chunked scan + skip + gate -> y (bf16)
  scan_pass1<<<dim3(DI_/256, G_, B_), 256, 0, stream>>>(dl_bf, u_bf, A_log, P, F);
  scan_pass2<<<(B_*DI_)/256, 256, 0, stream>>>(P, F, Sin);
  scan_pass3<<<dim3(DI_/256, G_, B_), 256, 0, stream>>>(dl_bf, u_bf, g_bf, Sin, A_log, Dp, y_bf);
  // 6) out = y @ out_proj_w^T  (fp32 output)
  gemm_bt<3><<<dim3(DM_/128, M_/128), 256, 0, stream>>>(
      y_bf, wo_bf, M_, DM_, DI_, (float*)d_out, nullptr, nullptr, nullptr);
}